// Round 3
// baseline (521.450 us; speedup 1.0000x reference)
//
#include <hip/hip_runtime.h>

// Correlation / cost-volume (kernel_size=1, stride=1, max_disp=4).
// out[b, dy*9+dx, y, x] = (1/C) * sum_c in1[b,c,y,x] * in2[b,c,y+dy-4,x+dx-4]
// B=8 C=192 H=W=128 fp32. No fp32 MFMA -> vector ALU.
// R2 post-mortem: 1 block/CU (256 blocks) exposed every barrier/load stall
// (VALUBusy 16.5%, all pipes ~80% idle). R3: tile 32x8 with HALF-WAVE = dy
// (32 lanes per dy, NT=288, dy = tid>>5 covers 0..8 exactly) keeps the
// 1 ds_read_b128 : 18 FMA ratio and acc=72, but gives 512 blocks = 2
// independent blocks/CU -> stalls of one block overlap compute of the other.
// LDS 45KB/block, launch_bounds(288,3) caps VGPR at 170 (need ~150).

constexpr int MAXD = 4;
constexpr int WIN  = 2 * MAXD + 1;      // 9
constexpr int Bn = 8, Cn = 192, Hn = 128, Wn = 128;

constexpr int XT = 32;                  // tile width
constexpr int YT = 8;                   // tile height
constexpr int XR = 8;                   // x pixels per thread
constexpr int XG = XT / XR;             // 4
constexpr int W2 = XT + 2 * MAXD;       // 40 staged cols
constexpr int H2 = YT + 2 * MAXD;       // 16 staged rows
constexpr int SP = 44;                  // padded LDS row stride (floats)
constexpr int CC = 8;                   // channels per chunk
constexpr int NT = XG * YT * WIN;       // 288 threads (4.5 waves, dy = tid>>5)
constexpr int KPR = W2 / 4;             // 10 float4 per row
constexpr int PIECES = CC * H2 * KPR;   // 1280
constexpr int PPT = (PIECES + NT - 1) / NT;  // 5 (last partial, guarded)
constexpr int NCHUNK = Cn / CC;         // 24
constexpr int BUF = CC * H2 * SP;       // 5632 floats per buffer

__global__ __launch_bounds__(NT, 3)     // cap VGPR ~170 so 2 blocks/CU fit
void corr_kernel(const float* __restrict__ in1,
                 const float* __restrict__ in2,
                 float* __restrict__ out)
{
    __shared__ float s2[2 * BUF];       // 45,056 B -> 2 blocks/CU (grid 2/CU)

    const int tid = threadIdx.x;
    const int tx  = tid & 3;            // x group (offset tx*8)
    const int ty  = (tid >> 2) & 7;     // y within tile
    const int dy  = tid >> 5;           // 0..8 (half-wave = dy)

    // ---- batch-per-XCD swizzle: xcd = flat%8 gets all 64 tiles of batch b ----
    const int fb = blockIdx.x + gridDim.x * (blockIdx.y + gridDim.y * blockIdx.z);
    const int b  = fb & 7;
    const int t  = fb >> 3;             // 0..63
    const int x0 = (t & 3) * XT;
    const int y0 = (t >> 2) * YT;

    const int x = x0 + tx * XR;
    const int y = y0 + ty;

    const float* in2b = in2 + (size_t)b * Cn * Hn * Wn;

    // ---- staging precompute: up to 5 pieces per thread (guarded) ----
    int soff[PPT];                      // LDS float offset
    int goff[PPT];                      // global float offset within chunk base
    int pbits = 0;                      // bit p: piece exists
    int zbits = 0;                      // bit p: data in-range (else zero-fill)
    #pragma unroll
    for (int p = 0; p < PPT; ++p) {
        int piece = tid + p * NT;
        if (piece < PIECES) pbits |= (1 << p);
        int c   = piece / (H2 * KPR);
        int rem = piece % (H2 * KPR);
        int row = rem / KPR;
        int k   = rem % KPR;
        int gy = y0 - MAXD + row;
        int gx = x0 - MAXD + 4 * k;
        int cy = gy < 0 ? 0 : (gy > Hn - 1 ? Hn - 1 : gy);
        int cx = gx < 0 ? 0 : (gx > Wn - 4 ? Wn - 4 : gx);
        soff[p] = (c * H2 + row) * SP + 4 * k;
        goff[p] = (c * Hn + cy) * Wn + cx;
        if (gy >= 0 && gy < Hn && gx >= 0 && gx <= Wn - 4) zbits |= (1 << p);
    }

    float acc[WIN][XR];
    #pragma unroll
    for (int dx = 0; dx < WIN; ++dx)
        #pragma unroll
        for (int i = 0; i < XR; ++i) acc[dx][i] = 0.f;

    const float* a_base = in1 + (((size_t)b * Cn) * Hn + y) * Wn + x;

    // ---- prologue: prefetch chunk 0 into registers (masked at load) ----
    float4 r[PPT];
    #pragma unroll
    for (int p = 0; p < PPT; ++p) {
        if (pbits & (1 << p)) {
            float4 v = *(const float4*)(in2b + goff[p]);
            float  m = (zbits >> p) & 1 ? 1.f : 0.f;
            v.x *= m; v.y *= m; v.z *= m; v.w *= m;
            r[p] = v;
        }
    }

    #pragma unroll 1
    for (int ci = 0; ci < NCHUNK; ++ci) {
        // write staged regs -> LDS buffer ci&1 (freed by barrier of iter ci-1)
        float* dst = &s2[(ci & 1) * BUF];
        #pragma unroll
        for (int p = 0; p < PPT; ++p)
            if (pbits & (1 << p)) *(float4*)(dst + soff[p]) = r[p];
        __syncthreads();   // single barrier per chunk

        // issue next chunk's global loads BEFORE compute (latency under FMAs)
        if (ci + 1 < NCHUNK) {
            const float* src = in2b + (size_t)(ci + 1) * CC * Hn * Wn;
            #pragma unroll
            for (int p = 0; p < PPT; ++p) {
                if (pbits & (1 << p)) {
                    float4 v = *(const float4*)(src + goff[p]);
                    float  m = (zbits >> p) & 1 ? 1.f : 0.f;
                    v.x *= m; v.y *= m; v.z *= m; v.w *= m;
                    r[p] = v;
                }
            }
        }

        // ---- compute 8 channels: per channel 4 ds_read_b128 -> 72 FMA ----
        const float* cur = &s2[(ci & 1) * BUF];
        const float* ap  = a_base + (size_t)ci * CC * Hn * Wn;
        #pragma unroll 4               // bound in-flight in1 loads
        for (int cc = 0; cc < CC; ++cc) {
            float4 a0 = *(const float4*)(ap + (size_t)cc * Hn * Wn);
            float4 a1 = *(const float4*)(ap + (size_t)cc * Hn * Wn + 4);
            const float* rp = cur + (cc * H2 + ty + dy) * SP + tx * XR;
            float fv[16];
            *(float4*)&fv[0]  = *(const float4*)(rp);
            *(float4*)&fv[4]  = *(const float4*)(rp + 4);
            *(float4*)&fv[8]  = *(const float4*)(rp + 8);
            *(float4*)&fv[12] = *(const float4*)(rp + 12);
            #pragma unroll
            for (int dx = 0; dx < WIN; ++dx) {
                acc[dx][0] += a0.x * fv[dx + 0];
                acc[dx][1] += a0.y * fv[dx + 1];
                acc[dx][2] += a0.z * fv[dx + 2];
                acc[dx][3] += a0.w * fv[dx + 3];
                acc[dx][4] += a1.x * fv[dx + 4];
                acc[dx][5] += a1.y * fv[dx + 5];
                acc[dx][6] += a1.z * fv[dx + 6];
                acc[dx][7] += a1.w * fv[dx + 7];
            }
        }
    }

    // ---- epilogue ----
    const float sc = 1.0f / (float)Cn;
    float* op = out + (((size_t)b * (WIN * WIN) + dy * WIN) * Hn + y) * Wn + x;
    #pragma unroll
    for (int dx = 0; dx < WIN; ++dx) {
        float4 v0 = { acc[dx][0] * sc, acc[dx][1] * sc, acc[dx][2] * sc, acc[dx][3] * sc };
        float4 v1 = { acc[dx][4] * sc, acc[dx][5] * sc, acc[dx][6] * sc, acc[dx][7] * sc };
        *(float4*)(op + (size_t)dx * Hn * Wn)     = v0;
        *(float4*)(op + (size_t)dx * Hn * Wn + 4) = v1;
    }
}

extern "C" void kernel_launch(void* const* d_in, const int* in_sizes, int n_in,
                              void* d_out, int out_size, void* d_ws, size_t ws_size,
                              hipStream_t stream) {
    const float* in1 = (const float*)d_in[0];
    const float* in2 = (const float*)d_in[1];
    float* out = (float*)d_out;
    dim3 grid(Wn / XT, Hn / YT, Bn);   // 4 x 16 x 8 = 512 blocks = 2/CU
    corr_kernel<<<grid, NT, 0, stream>>>(in1, in2, out);
}

// Round 4
// 500.987 us; speedup vs baseline: 1.0408x; 1.0408x over previous
//
#include <hip/hip_runtime.h>

// Correlation / cost-volume (kernel_size=1, stride=1, max_disp=4).
// out[b, dy*9+dx, y, x] = (1/C) * sum_c in1[b,c,y,x] * in2[b,c,y+dy-4,x+dx-4]
// B=8 C=192 H=W=128 fp32. No fp32 MFMA -> vector ALU.
// R1-R3 post-mortem: every XR=8 variant pinned at VGPR=84 < the ~130 the
// acc[9][8] design needs -> spill (R1: 908MB HBM scratch; R2/R3: hidden in
// L2, visible as VALUBusy 10-17% latency collapse). The register-feasible
// champion shape (XR=4, acc=36, VGPR 52) wins. This version keeps that
// shape and fixes its measured defects: SP=28 padding (4-way -> ~2-way
// conflicts), double-buffered LDS (24 barriers instead of 48) with
// reg-staged in2 prefetch, 2-deep rolling in1 register pipeline, and
// batch-per-XCD swizzle for L2 locality.

constexpr int MAXD = 4;
constexpr int WIN  = 2 * MAXD + 1;      // 9
constexpr int Bn = 8, Cn = 192, Hn = 128, Wn = 128;

constexpr int XT = 16, YT = 16, XR = 4;
constexpr int XG = XT / XR;             // 4
constexpr int W2 = XT + 2 * MAXD;       // 24 staged cols (data)
constexpr int H2 = YT + 2 * MAXD;       // 24 staged rows
constexpr int SP = 28;                  // padded stride: starts {28u%32} = 8 values -> ~2-way (free)
constexpr int CC = 8;                   // channels per chunk
constexpr int NT = XG * YT * WIN;       // 576 threads = 9 waves (wave id == dy)
constexpr int KPR = W2 / 4;             // 6 float4 per staged row
constexpr int PIECES = CC * H2 * KPR;   // 1152
constexpr int PPT = PIECES / NT;        // 2 (exact)
constexpr int NCHUNK = Cn / CC;         // 24
constexpr int BUF = CC * H2 * SP;       // 5376 floats per buffer

__global__ __launch_bounds__(NT, 5)     // 5 waves/EU min -> VGPR cap 102; need ~80
void corr_kernel(const float* __restrict__ in1,
                 const float* __restrict__ in2,
                 float* __restrict__ out)
{
    __shared__ float s2[2 * BUF];       // 43,008 B -> 2 blocks/CU fit (86KB)

    const int tid = threadIdx.x;
    const int tx  = tid & 3;            // x group (offset tx*4)
    const int ty  = (tid >> 2) & 15;    // y within tile
    const int g   = tid >> 6;           // wave id == dy (0..8)

    // ---- batch-per-XCD swizzle: fb%8 (== bx == typ. XCD) = batch ----
    const int fb = blockIdx.x + gridDim.x * (blockIdx.y + gridDim.y * blockIdx.z);
    const int b  = fb & 7;
    const int t  = fb >> 3;             // 0..63 tile index
    const int x0 = (t & 7) * XT;
    const int y0 = (t >> 3) * YT;

    const int x = x0 + tx * XR;
    const int y = y0 + ty;

    const float* in2b = in2 + (size_t)b * Cn * Hn * Wn;
    const size_t CH = (size_t)Hn * Wn;

    // ---- staging precompute: 2 pieces per thread (exact) ----
    int soff[PPT], goff[PPT];
    int mb = 0;                          // validity bits (4-aligned => per-float4)
    #pragma unroll
    for (int p = 0; p < PPT; ++p) {
        int piece = tid + p * NT;
        int c   = piece / (H2 * KPR);
        int rem = piece % (H2 * KPR);
        int row = rem / KPR;
        int k   = rem % KPR;
        int gy = y0 - MAXD + row;
        int gx = x0 - MAXD + 4 * k;
        int cy = gy < 0 ? 0 : (gy > Hn - 1 ? Hn - 1 : gy);
        int cx = gx < 0 ? 0 : (gx > Wn - 4 ? Wn - 4 : gx);
        soff[p] = (c * H2 + row) * SP + 4 * k;
        goff[p] = (c * Hn + cy) * Wn + cx;
        if (gy >= 0 && gy < Hn && gx >= 0 && gx <= Wn - 4) mb |= (1 << p);
    }

    float acc[WIN][XR];
    #pragma unroll
    for (int dx = 0; dx < WIN; ++dx)
        #pragma unroll
        for (int i = 0; i < XR; ++i) acc[dx][i] = 0.f;

    const float* a_base = in1 + (((size_t)b * Cn) * Hn + y) * Wn + x;

    // ---- in1 rolling 2-deep register pipeline (all 9 waves read identical
    //      addresses -> L1 broadcast; load issued 2 channels before use) ----
    float4 aq0 = *(const float4*)(a_base);
    float4 aq1 = *(const float4*)(a_base + CH);

    // ---- in2 chunk-0 prefetch (masked at load) ----
    float4 r[PPT];
    #pragma unroll
    for (int p = 0; p < PPT; ++p) {
        float4 v = *(const float4*)(in2b + goff[p]);
        float  m = (mb >> p) & 1 ? 1.f : 0.f;
        v.x *= m; v.y *= m; v.z *= m; v.w *= m;
        r[p] = v;
    }

    #pragma unroll 1
    for (int ci = 0; ci < NCHUNK; ++ci) {
        // write staged regs -> LDS buffer ci&1 (safe: barrier k+1 separates
        // iter-k reads of this buffer from iter-k+2 writes)
        float* dst = &s2[(ci & 1) * BUF];
        #pragma unroll
        for (int p = 0; p < PPT; ++p) *(float4*)(dst + soff[p]) = r[p];
        __syncthreads();                // single barrier per chunk

        // issue next chunk's in2 loads; consumed one full chunk later
        if (ci + 1 < NCHUNK) {
            const float* src = in2b + (size_t)(ci + 1) * CC * CH;
            #pragma unroll
            for (int p = 0; p < PPT; ++p) {
                float4 v = *(const float4*)(src + goff[p]);
                float  m = (mb >> p) & 1 ? 1.f : 0.f;
                v.x *= m; v.y *= m; v.z *= m; v.w *= m;
                r[p] = v;
            }
        }

        // ---- compute 8 channels: 3 ds_read_b128 + 36 FMA per channel ----
        const float* cur = &s2[(ci & 1) * BUF];
        #pragma unroll
        for (int cc = 0; cc < CC; ++cc) {
            float4 av = (cc & 1) ? aq1 : aq0;       // value loaded 2 channels ago
            int cn = ci * CC + cc + 2;              // issue channel c+2 now
            cn = cn > Cn - 1 ? Cn - 1 : cn;         // clamp (branch-free tail)
            if (cc & 1) aq1 = *(const float4*)(a_base + (size_t)cn * CH);
            else        aq0 = *(const float4*)(a_base + (size_t)cn * CH);

            const float* rp = cur + (cc * H2 + ty + g) * SP + tx * XR;
            float fv[12];
            *(float4*)&fv[0] = *(const float4*)(rp);
            *(float4*)&fv[4] = *(const float4*)(rp + 4);
            *(float4*)&fv[8] = *(const float4*)(rp + 8);
            #pragma unroll
            for (int dx = 0; dx < WIN; ++dx) {
                acc[dx][0] += av.x * fv[dx + 0];
                acc[dx][1] += av.y * fv[dx + 1];
                acc[dx][2] += av.z * fv[dx + 2];
                acc[dx][3] += av.w * fv[dx + 3];
            }
        }
    }

    // ---- epilogue ----
    const float sc = 1.0f / (float)Cn;
    float* op = out + (((size_t)b * (WIN * WIN) + g * WIN) * Hn + y) * Wn + x;
    #pragma unroll
    for (int dx = 0; dx < WIN; ++dx) {
        float4 v = { acc[dx][0] * sc, acc[dx][1] * sc,
                     acc[dx][2] * sc, acc[dx][3] * sc };
        *(float4*)(op + (size_t)dx * CH) = v;
    }
}

extern "C" void kernel_launch(void* const* d_in, const int* in_sizes, int n_in,
                              void* d_out, int out_size, void* d_ws, size_t ws_size,
                              hipStream_t stream) {
    const float* in1 = (const float*)d_in[0];
    const float* in2 = (const float*)d_in[1];
    float* out = (float*)d_out;
    dim3 grid(Wn / XT, Hn / YT, Bn);   // 8 x 8 x 8 = 512 blocks = 2/CU
    corr_kernel<<<grid, NT, 0, stream>>>(in1, in2, out);
}

// Round 5
// 279.803 us; speedup vs baseline: 1.8636x; 1.7905x over previous
//
#include <hip/hip_runtime.h>

// Correlation / cost-volume (kernel_size=1, stride=1, max_disp=4).
// out[b, dy*9+dx, y, x] = (1/C) * sum_c in1[b,c,y,x] * in2[b,c,y+dy-4,x+dx-4]
// B=8 C=192 H=W=128 fp32. No fp32 MFMA -> vector ALU.
//
// R1-R4 lessons baked in:
//  * Register-feasible shape only: XR=4, acc[9][4]=36, plain
//    __launch_bounds__(NT). Any min-occupancy second arg mis-caps VGPR
//    (R4: (NT,5) -> 48 regs -> 160MB scratch evictions). Design for <=84.
//  * LDS bank model (validated by SP=24 vs SP=28 conflict counts): b128
//    issues in 8-lane phases; conflict-free needs row stride == 4 (mod 8)
//    16B-quads -> SP = 48 floats. SP=24 cost 1.06e7 cyc, SP=28 1.24e7.
//  * Double-buffer + 1 barrier/chunk is race-free (write buf[ci&1] ->
//    barrier -> prefetch ci+1 -> compute): any wave past barrier(ci+1)
//    has finished reading buf[ci&1] from iter ci.
//  * Batch-per-XCD swizzle verified: FETCH 270 -> 118 MB.

constexpr int MAXD = 4;
constexpr int WIN  = 2 * MAXD + 1;      // 9
constexpr int Bn = 8, Cn = 192, Hn = 128, Wn = 128;

constexpr int XT = 16, YT = 16, XR = 4;
constexpr int XG = XT / XR;             // 4
constexpr int W2 = XT + 2 * MAXD;       // 24 data cols staged
constexpr int H2 = YT + 2 * MAXD;       // 24 rows staged
constexpr int SP = 48;                  // row stride (floats) == 12 quads == 4 mod 8 -> phase-conflict-free
constexpr int CC = 8;                   // channels per chunk
constexpr int NT = XG * YT * WIN;       // 576 threads = 9 waves (wave id == dy)
constexpr int KPR = W2 / 4;             // 6 float4 per staged row
constexpr int PIECES = CC * H2 * KPR;   // 1152
constexpr int PPT = PIECES / NT;        // 2 (exact)
constexpr int NCHUNK = Cn / CC;         // 24
constexpr int BUF = CC * H2 * SP;       // 9216 floats = 36,864 B per buffer

__global__ __launch_bounds__(NT)        // plain: compiler cap ~84, need ~75
void corr_kernel(const float* __restrict__ in1,
                 const float* __restrict__ in2,
                 float* __restrict__ out)
{
    __shared__ float s2[2 * BUF];       // 73,728 B -> 2 blocks/CU (147 KB)

    const int tid = threadIdx.x;
    const int tx  = tid & 3;            // x group (offset tx*4)
    const int ty  = (tid >> 2) & 15;    // y within tile
    const int g   = tid >> 6;           // wave id == dy (0..8)

    // ---- batch-per-XCD swizzle: fb%8 = batch, all 64 tiles of b on one XCD ----
    const int fb = blockIdx.x + gridDim.x * (blockIdx.y + gridDim.y * blockIdx.z);
    const int b  = fb & 7;
    const int t  = fb >> 3;             // 0..63 tile index
    const int x0 = (t & 7) * XT;
    const int y0 = (t >> 3) * YT;

    const int x = x0 + tx * XR;
    const int y = y0 + ty;

    const float* in2b = in2 + (size_t)b * Cn * Hn * Wn;
    const size_t CH = (size_t)Hn * Wn;

    // ---- staging precompute: 2 pieces per thread (exact) ----
    int soff[PPT], goff[PPT];
    int mb = 0;                         // validity bits (4-aligned => per-float4)
    #pragma unroll
    for (int p = 0; p < PPT; ++p) {
        int piece = tid + p * NT;
        int c   = piece / (H2 * KPR);
        int rem = piece % (H2 * KPR);
        int row = rem / KPR;
        int k   = rem % KPR;
        int gy = y0 - MAXD + row;
        int gx = x0 - MAXD + 4 * k;
        int cy = gy < 0 ? 0 : (gy > Hn - 1 ? Hn - 1 : gy);
        int cx = gx < 0 ? 0 : (gx > Wn - 4 ? Wn - 4 : gx);
        soff[p] = (c * H2 + row) * SP + 4 * k;
        goff[p] = (c * Hn + cy) * Wn + cx;
        if (gy >= 0 && gy < Hn && gx >= 0 && gx <= Wn - 4) mb |= (1 << p);
    }

    float acc[WIN][XR];
    #pragma unroll
    for (int dx = 0; dx < WIN; ++dx)
        #pragma unroll
        for (int i = 0; i < XR; ++i) acc[dx][i] = 0.f;

    const float* a_base = in1 + (((size_t)b * Cn) * Hn + y) * Wn + x;

    // ---- prologue: prefetch chunk 0 into registers (masked at load) ----
    float4 r[PPT];
    #pragma unroll
    for (int p = 0; p < PPT; ++p) {
        float4 v = *(const float4*)(in2b + goff[p]);
        float  m = (mb >> p) & 1 ? 1.f : 0.f;
        v.x *= m; v.y *= m; v.z *= m; v.w *= m;
        r[p] = v;
    }

    #pragma unroll 1
    for (int ci = 0; ci < NCHUNK; ++ci) {
        // write staged regs -> LDS buffer ci&1
        float* dst = &s2[(ci & 1) * BUF];
        #pragma unroll
        for (int p = 0; p < PPT; ++p) *(float4*)(dst + soff[p]) = r[p];
        __syncthreads();                // single barrier per chunk

        // issue next chunk's in2 loads; consumed one full chunk later
        if (ci + 1 < NCHUNK) {
            const float* src = in2b + (size_t)(ci + 1) * CC * CH;
            #pragma unroll
            for (int p = 0; p < PPT; ++p) {
                float4 v = *(const float4*)(src + goff[p]);
                float  m = (mb >> p) & 1 ? 1.f : 0.f;
                v.x *= m; v.y *= m; v.z *= m; v.w *= m;
                r[p] = v;
            }
        }

        // ---- compute 8 channels: 3 ds_read_b128 + 36 FMA per channel ----
        const float* cur = &s2[(ci & 1) * BUF];
        #pragma unroll
        for (int cc = 0; cc < CC; ++cc) {
            float4 av = *(const float4*)(a_base + (size_t)(ci * CC + cc) * CH);
            const float* rp = cur + (cc * H2 + ty + g) * SP + tx * XR;
            float fv[12];
            *(float4*)&fv[0] = *(const float4*)(rp);
            *(float4*)&fv[4] = *(const float4*)(rp + 4);
            *(float4*)&fv[8] = *(const float4*)(rp + 8);
            #pragma unroll
            for (int dx = 0; dx < WIN; ++dx) {
                acc[dx][0] += av.x * fv[dx + 0];
                acc[dx][1] += av.y * fv[dx + 1];
                acc[dx][2] += av.z * fv[dx + 2];
                acc[dx][3] += av.w * fv[dx + 3];
            }
        }
    }

    // ---- epilogue ----
    const float sc = 1.0f / (float)Cn;
    float* op = out + (((size_t)b * (WIN * WIN) + g * WIN) * Hn + y) * Wn + x;
    #pragma unroll
    for (int dx = 0; dx < WIN; ++dx) {
        float4 v = { acc[dx][0] * sc, acc[dx][1] * sc,
                     acc[dx][2] * sc, acc[dx][3] * sc };
        *(float4*)(op + (size_t)dx * CH) = v;
    }
}

extern "C" void kernel_launch(void* const* d_in, const int* in_sizes, int n_in,
                              void* d_out, int out_size, void* d_ws, size_t ws_size,
                              hipStream_t stream) {
    const float* in1 = (const float*)d_in[0];
    const float* in2 = (const float*)d_in[1];
    float* out = (float*)d_out;
    dim3 grid(Wn / XT, Hn / YT, Bn);   // 8 x 8 x 8 = 512 blocks = 2/CU
    corr_kernel<<<grid, NT, 0, stream>>>(in1, in2, out);
}